// Round 12
// baseline (86.706 us; speedup 1.0000x reference)
//
#include <hip/hip_runtime.h>
#include <stdint.h>

#define T_LEN 8192
#define NSTEP 8190   // T - 2 interior samples
#define NB 16
#define NCH 256
#define JBLKS 32     // ceil(NSTEP/256) decide blocks per batch

// ---------------- threefry2x32 (exact JAX cipher) ----------------
__device__ __forceinline__ uint32_t rotl32(uint32_t v, int r) {
  return (v << r) | (v >> (32 - r));
}

__device__ __forceinline__ void tf2x32(uint32_t k0, uint32_t k1, uint32_t x0, uint32_t x1,
                                       uint32_t& o0, uint32_t& o1) {
  uint32_t ks2 = k0 ^ k1 ^ 0x1BD11BDAu;
  x0 += k0; x1 += k1;
#define RR(r) { x0 += x1; x1 = rotl32(x1, (r)); x1 ^= x0; }
  RR(13) RR(15) RR(26) RR(6)   x0 += k1;  x1 += ks2 + 1u;
  RR(17) RR(29) RR(16) RR(24)  x0 += ks2; x1 += k0 + 2u;
  RR(13) RR(15) RR(26) RR(6)   x0 += k0;  x1 += k1 + 3u;
  RR(17) RR(29) RR(16) RR(24)  x0 += k1;  x1 += ks2 + 4u;
  RR(13) RR(15) RR(26) RR(6)   x0 += ks2; x1 += k0 + 5u;
#undef RR
  o0 = x0; o1 = x1;
}

// ---------------- 9-state Markov map helpers (VERIFIED r4) ----------------
__device__ __forceinline__ uint64_t compose_map(uint64_t f, uint64_t g) {
  uint64_t r = 0;
#pragma unroll
  for (int st = 0; st < 9; ++st) {
    uint32_t fs = (uint32_t)((f >> (4 * st)) & 15u);
    uint32_t gs = (uint32_t)((g >> (4 * fs)) & 15u);
    r |= ((uint64_t)gs) << (4 * st);
  }
  return r;
}

__device__ __forceinline__ uint64_t shflup64(uint64_t v, int delta) {
  int lo = __shfl_up((int)(uint32_t)v, delta, 64);
  int hi = __shfl_up((int)(uint32_t)(v >> 32), delta, 64);
  return (((uint64_t)(uint32_t)hi) << 32) | (uint32_t)lo;
}

#define IDENT_MAP 0x876543210ull

// ---------------- K1: fused decide + last-block-per-batch scan -------------
// Decide math is byte-identical to the r3-VERIFIED kernel (PARTITIONABLE
// threefry: split(key,n)[i] = cipher(key,(0,i)); random_bits = y0^y1 of
// cipher(key,(0,c))). After a block writes its 256-step decision chunk it
// bumps cnt[b]; the block seeing old==JBLKS-1 runs the r4-VERIFIED scan for
// batch b (overlapped with other batches' decide work). No spin-waits.
__global__ __launch_bounds__(256) void k_prep(const float* __restrict__ probs,
                                              uint8_t* __restrict__ dec,
                                              uint8_t* __restrict__ dbuf,
                                              uint32_t* __restrict__ cnt) {
  const int tid = threadIdx.x;
  const int b = blockIdx.y;
  const int j = blockIdx.x * 256 + tid;

  // ---- decide phase (VERIFIED r3) ----
  if (j < NSTEP) {
    uint32_t kb0, kb1;
    tf2x32(0u, 42u, 0u, (uint32_t)b, kb0, kb1);      // split(key(42),16)[b]
    uint32_t s0, s1;
    tf2x32(kb0, kb1, 0u, (uint32_t)j, s0, s1);       // split(kb,8190)[j]

    uint32_t bits[3];
    {
      uint32_t y0, y1;
      tf2x32(s0, s1, 0u, 0u, y0, y1); bits[0] = y0 ^ y1;
      tf2x32(s0, s1, 0u, 1u, y0, y1); bits[1] = y0 ^ y1;
      tf2x32(s0, s1, 0u, 2u, y0, y1); bits[2] = y0 ^ y1;
    }

    double g[3];
#pragma unroll
    for (int c = 0; c < 3; ++c) {
      uint32_t k = bits[c] >> 9;                            // 23-bit mantissa sample
      float u = k ? (float)k * 0x1p-23f : 1.17549435e-38f;  // exact JAX uniform value
      g[c] = -log(-log((double)u));
    }

    double lp = log((double)probs[0]);
    double ls = log((double)probs[1]);
    double l1 = log((double)probs[2 * 9 + 1 * 3 + 1]);
    double l2 = log((double)probs[2 * 9 + 1 * 3 + 2]);

    double v0 = lp + g[0], v1 = ls + g[1], v2 = lp + g[2];
    int n = 0; double best = v0;
    if (v1 > best) { n = 1; best = v1; }
    if (v2 > best) { n = 2; }
    int sp = (l1 + g[1] >= l2 + g[2]) ? 1 : 2;          // argmax tie -> first

    dec[b * NSTEP + j] = (uint8_t)(n | (sp << 2));
  }

  // ---- completion count: is this the last decide block of batch b? ----
  __shared__ int do_scan;
  __syncthreads();                 // all dec writes of this block issued
  if (tid == 0) {
    __threadfence();               // publish dec chunk (device scope)
    uint32_t old = atomicAdd(&cnt[b], 1u);
    do_scan = (old == JBLKS - 1);
  }
  __syncthreads();
  if (!do_scan) return;
  __threadfence();                 // acquire: see all 32 chunks of batch b

  // ---- scan phase (VERIFIED r4), batch b ----
  const int lane = tid & 63, wave = tid >> 6;
  const int begin = tid * 32;
  const uint8_t* row = dec + b * NSTEP;

  uint64_t M = IDENT_MAP;
#pragma unroll
  for (int t = 0; t < 32; ++t) {
    int step = begin + t;
    if (step < NSTEP) {
      int d = row[step];
      uint32_t n = d & 3u, s = (d >> 2) & 3u;
      uint64_t Mn = 0;
#pragma unroll
      for (int st = 0; st < 9; ++st) {
        uint32_t u = (uint32_t)((M >> (4 * st)) & 15u);
        uint32_t div3 = (u * 11u) >> 5;          // u/3 for u<9
        uint32_t p1 = u - 3u * div3;
        uint32_t jj = (u == 7u) ? s : n;
        Mn |= ((uint64_t)(p1 * 3u + jj)) << (4 * st);
      }
      M = Mn;
    }
  }

  uint64_t I = M;
#pragma unroll
  for (int off = 1; off < 64; off <<= 1) {
    uint64_t Mp = shflup64(I, off);
    uint64_t c = compose_map(Mp, I);
    I = (lane >= off) ? c : I;
  }

  __shared__ uint64_t wmap[4];
  if (lane == 63) wmap[wave] = I;
  __syncthreads();

  uint64_t W = IDENT_MAP;
  for (int w = 0; w < wave; ++w) W = compose_map(W, wmap[w]);
  uint64_t E = shflup64(I, 1);
  if (lane == 0) E = IDENT_MAP;
  uint64_t X = compose_map(W, E);

  int state = (int)((X >> (4 * 4)) & 15u);  // applied to initial chain state (1,1)=4

  uint8_t* orow = dbuf + b * T_LEN;
#pragma unroll
  for (int t = 0; t < 32; ++t) {
    int step = begin + t;
    if (step < NSTEP) {
      int d = row[step];
      uint32_t n = d & 3u, s = (d >> 2) & 3u;
      uint32_t jj = (state == 7) ? s : n;
      uint32_t div3 = ((uint32_t)state * 11u) >> 5;
      uint32_t p1 = (uint32_t)state - 3u * div3;
      state = (int)(p1 * 3u + jj);
      orow[step + 1] = (uint8_t)jj;
    }
  }
  if (tid == 0) { orow[0] = 1; orow[T_LEN - 1] = 1; }   // forced j=1 -> src=t
}

// ---------------- K3: copy-like shift-select gather (VERIFIED r8, best) ----
// out[b,i,t] = x[b,i,t+d-1], d in {0,1,2}. One block = one 4 KB row-chunk;
// per thread ONE float4 load + ONE nt float4 store (+4 B dbuf). Halos via
// LDS neighbor exchange; block-edge values via 2 exec-masked scalar loads.
typedef float f32x4 __attribute__((ext_vector_type(4)));

__global__ __launch_bounds__(256) void k_gather(const float* __restrict__ x,
                                                const uint8_t* __restrict__ dbuf,
                                                float* __restrict__ out) {
  __shared__ float shx[256];   // each thread's v.x
  __shared__ float shw[256];   // each thread's v.w

  const int bid = blockIdx.x;
  const int tc = bid & 7;            // t-chunk (fastest -> contiguous sweep)
  const int i  = (bid >> 3) & 255;   // channel
  const int b  = bid >> 11;          // batch
  const int tid = threadIdx.x;
  const int t0 = tc * 1024 + tid * 4;

  const uchar4 du = *(const uchar4*)(dbuf + b * T_LEN + t0);
  const float* __restrict__ xr = x + ((size_t)(b * NCH + i)) * T_LEN;

  float4 v = *(const float4*)(xr + t0);

  float Le = 0.0f, Re = 0.0f;
  if (tid == 0)   Le = (t0 > 0) ? xr[t0 - 1] : 0.0f;
  if (tid == 255) Re = (t0 + 4 < T_LEN) ? xr[t0 + 4] : 0.0f;

  shx[tid] = v.x;
  shw[tid] = v.w;
  __syncthreads();

  const float L = (tid == 0)   ? Le : shw[tid - 1];
  const float R = (tid == 255) ? Re : shx[tid + 1];

  f32x4 o;
  o.x = (du.x == 0) ? L   : ((du.x == 1) ? v.x : v.y);
  o.y = (du.y == 0) ? v.x : ((du.y == 1) ? v.y : v.z);
  o.z = (du.z == 0) ? v.y : ((du.z == 1) ? v.z : v.w);
  o.w = (du.w == 0) ? v.z : ((du.w == 1) ? v.w : R);
  __builtin_nontemporal_store(o, (f32x4*)(out + ((size_t)(b * NCH + i)) * T_LEN + t0));
}

extern "C" void kernel_launch(void* const* d_in, const int* in_sizes, int n_in,
                              void* d_out, int out_size, void* d_ws, size_t ws_size,
                              hipStream_t stream) {
  const float* x = (const float*)d_in[0];
  const float* probs = (const float*)d_in[1];
  float* out = (float*)d_out;

  uint8_t* dec = (uint8_t*)d_ws;                         // 16*8190 = 131040 B
  uint8_t* dbuf = (uint8_t*)d_ws + 131072;               // 16*8192 = 128 KiB
  uint32_t* cnt = (uint32_t*)((char*)d_ws + 262144);     // 16 counters

  hipMemsetAsync(cnt, 0, NB * sizeof(uint32_t), stream); // graph-safe

  dim3 g1(JBLKS, NB);
  k_prep<<<g1, 256, 0, stream>>>(probs, dec, dbuf, cnt);

  // 16 batches * 256 channels * 8 t-chunks = 32768 blocks, linear sweep
  k_gather<<<NB * NCH * 8, 256, 0, stream>>>(x, dbuf, out);
}

// Round 13
// 65.059 us; speedup vs baseline: 1.3327x; 1.3327x over previous
//
#include <hip/hip_runtime.h>
#include <stdint.h>

#define T_LEN 8192
#define NSTEP 8190   // T - 2 interior samples
#define NB 16
#define NCH 256

// ---------------- threefry2x32 (exact JAX cipher) ----------------
__device__ __forceinline__ uint32_t rotl32(uint32_t v, int r) {
  return (v << r) | (v >> (32 - r));
}

__device__ __forceinline__ void tf2x32(uint32_t k0, uint32_t k1, uint32_t x0, uint32_t x1,
                                       uint32_t& o0, uint32_t& o1) {
  uint32_t ks2 = k0 ^ k1 ^ 0x1BD11BDAu;
  x0 += k0; x1 += k1;
#define RR(r) { x0 += x1; x1 = rotl32(x1, (r)); x1 ^= x0; }
  RR(13) RR(15) RR(26) RR(6)   x0 += k1;  x1 += ks2 + 1u;
  RR(17) RR(29) RR(16) RR(24)  x0 += ks2; x1 += k0 + 2u;
  RR(13) RR(15) RR(26) RR(6)   x0 += k0;  x1 += k1 + 3u;
  RR(17) RR(29) RR(16) RR(24)  x0 += k1;  x1 += ks2 + 4u;
  RR(13) RR(15) RR(26) RR(6)   x0 += ks2; x1 += k0 + 5u;
#undef RR
  o0 = x0; o1 = x1;
}

// ---------------- K1: per-step categorical decisions (VERIFIED r3) ----------
// PARTITIONABLE threefry semantics (JAX >= 0.4.36 default):
//   split(key, n)[i]          = full cipher pair threefry2x32(key, (hi32(i), lo32(i)))
//   random_bits(key,32,(m,))  = bits1 ^ bits2 of cipher(key, (0, c)), c = 0..m-1
// Record BOTH possible decisions: n (normal row), sp (special row (2,1)),
// packed as byte n | (sp<<2).
__global__ __launch_bounds__(256) void k_decide(const float* __restrict__ probs,
                                                uint8_t* __restrict__ dec) {
  int j = blockIdx.x * 256 + threadIdx.x;
  int b = blockIdx.y;
  if (j >= NSTEP) return;

  uint32_t kb0, kb1;
  tf2x32(0u, 42u, 0u, (uint32_t)b, kb0, kb1);      // split(key(42),16)[b]
  uint32_t s0, s1;
  tf2x32(kb0, kb1, 0u, (uint32_t)j, s0, s1);       // split(kb,8190)[j]

  uint32_t bits[3];
  {
    uint32_t y0, y1;
    tf2x32(s0, s1, 0u, 0u, y0, y1); bits[0] = y0 ^ y1;
    tf2x32(s0, s1, 0u, 1u, y0, y1); bits[1] = y0 ^ y1;
    tf2x32(s0, s1, 0u, 2u, y0, y1); bits[2] = y0 ^ y1;
  }

  double g[3];
#pragma unroll
  for (int c = 0; c < 3; ++c) {
    uint32_t k = bits[c] >> 9;                            // 23-bit mantissa sample
    float u = k ? (float)k * 0x1p-23f : 1.17549435e-38f;  // exact JAX uniform value
    g[c] = -log(-log((double)u));
  }

  double lp = log((double)probs[0]);
  double ls = log((double)probs[1]);
  double l1 = log((double)probs[2 * 9 + 1 * 3 + 1]);
  double l2 = log((double)probs[2 * 9 + 1 * 3 + 2]);

  double v0 = lp + g[0], v1 = ls + g[1], v2 = lp + g[2];
  int n = 0; double best = v0;
  if (v1 > best) { n = 1; best = v1; }
  if (v2 > best) { n = 2; }
  int sp = (l1 + g[1] >= l2 + g[2]) ? 1 : 2;          // argmax tie -> first

  dec[b * NSTEP + j] = (uint8_t)(n | (sp << 2));
}

// ---------------- K2: parallel Markov scan -> delta bytes (VERIFIED r4) ----
// State u = p2*3 + p1 in [0,9). Step: j = (u==7) ? spec : norm; u' = (u%3)*3 + j.
// Output: dbuf[b][t] = j in {0,1,2}; gather source = t + j - 1.
__device__ __forceinline__ uint64_t compose_map(uint64_t f, uint64_t g) {
  uint64_t r = 0;
#pragma unroll
  for (int st = 0; st < 9; ++st) {
    uint32_t fs = (uint32_t)((f >> (4 * st)) & 15u);
    uint32_t gs = (uint32_t)((g >> (4 * fs)) & 15u);
    r |= ((uint64_t)gs) << (4 * st);
  }
  return r;
}

__device__ __forceinline__ uint64_t shflup64(uint64_t v, int delta) {
  int lo = __shfl_up((int)(uint32_t)v, delta, 64);
  int hi = __shfl_up((int)(uint32_t)(v >> 32), delta, 64);
  return (((uint64_t)(uint32_t)hi) << 32) | (uint32_t)lo;
}

#define IDENT_MAP 0x876543210ull

__global__ __launch_bounds__(256) void k_scan(const uint8_t* __restrict__ dec,
                                              uint8_t* __restrict__ dbuf) {
  int b = blockIdx.x;
  int tid = threadIdx.x;
  int lane = tid & 63, wave = tid >> 6;
  int begin = tid * 32;
  const uint8_t* row = dec + b * NSTEP;

  // phase 1: build this chunk's 9-state map
  uint64_t M = IDENT_MAP;
#pragma unroll
  for (int t = 0; t < 32; ++t) {
    int step = begin + t;
    if (step < NSTEP) {
      int d = row[step];
      uint32_t n = d & 3u, s = (d >> 2) & 3u;
      uint64_t Mn = 0;
#pragma unroll
      for (int st = 0; st < 9; ++st) {
        uint32_t u = (uint32_t)((M >> (4 * st)) & 15u);
        uint32_t div3 = (u * 11u) >> 5;          // u/3 for u<9
        uint32_t p1 = u - 3u * div3;
        uint32_t jj = (u == 7u) ? s : n;
        Mn |= ((uint64_t)(p1 * 3u + jj)) << (4 * st);
      }
      M = Mn;
    }
  }

  // phase 2a: wave-inclusive scan
  uint64_t I = M;
#pragma unroll
  for (int off = 1; off < 64; off <<= 1) {
    uint64_t Mp = shflup64(I, off);
    uint64_t c = compose_map(Mp, I);
    I = (lane >= off) ? c : I;
  }

  __shared__ uint64_t wmap[4];
  if (lane == 63) wmap[wave] = I;
  __syncthreads();

  // phase 2b: exclusive prefix
  uint64_t W = IDENT_MAP;
  for (int w = 0; w < wave; ++w) W = compose_map(W, wmap[w]);
  uint64_t E = shflup64(I, 1);
  if (lane == 0) E = IDENT_MAP;
  uint64_t X = compose_map(W, E);

  int state = (int)((X >> (4 * 4)) & 15u);  // applied to initial chain state (1,1)=4

  // phase 3: replay chunk, emit delta bytes dbuf[b][step+1] = j
  uint8_t* orow = dbuf + b * T_LEN;
#pragma unroll
  for (int t = 0; t < 32; ++t) {
    int step = begin + t;
    if (step < NSTEP) {
      int d = row[step];
      uint32_t n = d & 3u, s = (d >> 2) & 3u;
      uint32_t jj = (state == 7) ? s : n;
      uint32_t div3 = ((uint32_t)state * 11u) >> 5;
      uint32_t p1 = (uint32_t)state - 3u * div3;
      state = (int)(p1 * 3u + jj);
      orow[step + 1] = (uint8_t)jj;
    }
  }
  if (tid == 0) { orow[0] = 1; orow[T_LEN - 1] = 1; }   // forced j=1 -> src=t
}

// ---------------- K3: copy-like shift-select gather (r8 best, 65.3 us) -----
// out[b,i,t] = x[b,i,t+d-1], d in {0,1,2}. One block = one 4 KB row-chunk;
// per thread ONE float4 load + ONE nt float4 store (+4 B dbuf, L2-hot).
// Halos via LDS neighbor exchange; block-edge values via 2 exec-masked
// scalar loads. Linear blockIdx sweeps contiguous memory.
typedef float f32x4 __attribute__((ext_vector_type(4)));

__global__ __launch_bounds__(256) void k_gather(const float* __restrict__ x,
                                                const uint8_t* __restrict__ dbuf,
                                                float* __restrict__ out) {
  __shared__ float shx[256];   // each thread's v.x
  __shared__ float shw[256];   // each thread's v.w

  const int bid = blockIdx.x;
  const int tc = bid & 7;            // t-chunk (fastest -> contiguous sweep)
  const int i  = (bid >> 3) & 255;   // channel
  const int b  = bid >> 11;          // batch
  const int tid = threadIdx.x;
  const int t0 = tc * 1024 + tid * 4;

  const uchar4 du = *(const uchar4*)(dbuf + b * T_LEN + t0);
  const float* __restrict__ xr = x + ((size_t)(b * NCH + i)) * T_LEN;

  float4 v = *(const float4*)(xr + t0);

  // block-edge halos (clamped at array ends; forced d=1 there => never selected)
  float Le = 0.0f, Re = 0.0f;
  if (tid == 0)   Le = (t0 > 0) ? xr[t0 - 1] : 0.0f;
  if (tid == 255) Re = (t0 + 4 < T_LEN) ? xr[t0 + 4] : 0.0f;

  shx[tid] = v.x;
  shw[tid] = v.w;
  __syncthreads();

  const float L = (tid == 0)   ? Le : shw[tid - 1];
  const float R = (tid == 255) ? Re : shx[tid + 1];

  f32x4 o;
  o.x = (du.x == 0) ? L   : ((du.x == 1) ? v.x : v.y);
  o.y = (du.y == 0) ? v.x : ((du.y == 1) ? v.y : v.z);
  o.z = (du.z == 0) ? v.y : ((du.z == 1) ? v.z : v.w);
  o.w = (du.w == 0) ? v.z : ((du.w == 1) ? v.w : R);
  __builtin_nontemporal_store(o, (f32x4*)(out + ((size_t)(b * NCH + i)) * T_LEN + t0));
}

extern "C" void kernel_launch(void* const* d_in, const int* in_sizes, int n_in,
                              void* d_out, int out_size, void* d_ws, size_t ws_size,
                              hipStream_t stream) {
  const float* x = (const float*)d_in[0];
  const float* probs = (const float*)d_in[1];
  float* out = (float*)d_out;

  uint8_t* dec = (uint8_t*)d_ws;                       // 16*8190 = 131040 B
  uint8_t* dbuf = (uint8_t*)d_ws + 131072;             // 16*8192 = 128 KiB

  dim3 g1((NSTEP + 255) / 256, NB);
  k_decide<<<g1, 256, 0, stream>>>(probs, dec);

  k_scan<<<NB, 256, 0, stream>>>(dec, dbuf);

  // 16 batches * 256 channels * 8 t-chunks = 32768 blocks, linear sweep
  k_gather<<<NB * NCH * 8, 256, 0, stream>>>(x, dbuf, out);
}